// Round 6
// baseline (299.508 us; speedup 1.0000x reference)
//
#include <hip/hip_runtime.h>
#include <hip/hip_bf16.h>

typedef unsigned short u16;
typedef unsigned int u32;
typedef __attribute__((ext_vector_type(8))) short bf16x8;
typedef __attribute__((ext_vector_type(4))) float f32x4;

#define S_LEN 4096
#define DHEAD 128
#define NHEAD 8
#define NBATCH 2

__device__ __forceinline__ u16 f2b(float f) {
  __hip_bfloat16 h = __float2bfloat16(f);
  return *(u16*)&h;
}

__device__ __forceinline__ f32x4 mfma16(bf16x8 a, bf16x8 b, f32x4 c) {
  return __builtin_amdgcn_mfma_f32_16x16x32_bf16(a, b, c, 0, 0, 0);
}

__device__ __forceinline__ f32x4 zero4() { f32x4 z = {0.f, 0.f, 0.f, 0.f}; return z; }

// ---------------- converts ----------------
__global__ void k_conv_x(const float* __restrict__ x, u16* __restrict__ xb,
                         u16* __restrict__ xT) {
  int idx = blockIdx.x * blockDim.x + threadIdx.x;
  float v = x[idx];
  u16 bv = f2b(v);
  xb[idx] = bv;
  int d = idx & 127;
  int bs = idx >> 7;
  int b = bs >> 12;
  int s = bs & 4095;
  xT[((size_t)b * DHEAD + d) * S_LEN + s] = bv;
}

__global__ void k_conv_w(const float* __restrict__ Wq, const float* __restrict__ Wk,
                         const float* __restrict__ Wo, u16* __restrict__ Wqt,
                         u16* __restrict__ Wkt, u16* __restrict__ WoB) {
  int idx = blockIdx.x * blockDim.x + threadIdx.x;
  int h = idx >> 14;
  int d = (idx >> 7) & 127;
  int e = idx & 127;
  int t = (h << 14) + (e << 7) + d;
  Wqt[t] = f2b(Wq[idx]);
  Wkt[t] = f2b(Wk[idx]);
  WoB[idx] = f2b(Wo[idx]);
}

// ---------------- Q/K projection: 4 waves/block ----------------
__global__ __launch_bounds__(256) void k_proj(const u16* __restrict__ xb,
                                              const u16* __restrict__ Wqt,
                                              const u16* __restrict__ Wkt,
                                              u16* __restrict__ Qb, u16* __restrict__ Kb) {
  int wid = threadIdx.x >> 6;
  int lane = threadIdx.x & 63;
  int qt = blockIdx.x * 4 + wid;
  int h = blockIdx.y, z = blockIdx.z;
  int b = z >> 1, w = z & 1;
  int row16 = lane & 15, kgrp = lane >> 4;
  int sb = qt * 32;
  const u16* xp = xb + ((size_t)b * S_LEN + sb) * DHEAD;
  bf16x8 a[2][4];
#pragma unroll
  for (int r = 0; r < 2; ++r)
#pragma unroll
    for (int kc = 0; kc < 4; ++kc)
      a[r][kc] = *(const bf16x8*)(xp + (r * 16 + row16) * DHEAD + kc * 32 + kgrp * 8);

  const u16* Wt = (w == 0 ? Wqt : Wkt) + (size_t)h * DHEAD * DHEAD;
  u16* Out = (w == 0 ? Qb : Kb) + ((size_t)(b * NHEAD + h) * S_LEN + sb) * DHEAD;
  f32x4 acc[2][8];
#pragma unroll
  for (int r = 0; r < 2; ++r)
#pragma unroll
    for (int nc = 0; nc < 8; ++nc) acc[r][nc] = zero4();
#pragma unroll
  for (int kc = 0; kc < 4; ++kc)
#pragma unroll
    for (int nc = 0; nc < 8; ++nc) {
      bf16x8 bw = *(const bf16x8*)(Wt + (nc * 16 + row16) * DHEAD + kc * 32 + kgrp * 8);
      acc[0][nc] = mfma16(a[0][kc], bw, acc[0][nc]);
      acc[1][nc] = mfma16(a[1][kc], bw, acc[1][nc]);
    }
#pragma unroll
  for (int r = 0; r < 2; ++r)
#pragma unroll
    for (int nc = 0; nc < 8; ++nc)
#pragma unroll
      for (int i = 0; i < 4; ++i)
        Out[(size_t)(r * 16 + kgrp * 4 + i) * DHEAD + nc * 16 + row16] =
            f2b(acc[r][nc][i]);
}

// ---------------- causal flash attention: 2-deep in-wave pipeline ----------------
// 1 wave per block; 32 q-rows; tiles processed in pairs so QK(t+1) MFMAs
// interleave with softmax(t) VALU and softmax(t+1) interleaves with PV(t).
__global__ __launch_bounds__(64) void k_attn(const u16* __restrict__ Qb,
                                             const u16* __restrict__ Kb,
                                             const u16* __restrict__ xT,
                                             u16* __restrict__ Yb) {
  int p = blockIdx.x;
  int xcd = p & 7;
  int j = p >> 3;                        // 0..255
  int pair = xcd + (j >= 128 ? 8 : 0);   // 0..15 (same (b,h) per XCD)
  int qt = 127 - (j & 127);              // longest first (LPT)
  int b = pair >> 3;
  int h = pair & 7;

  int lane = threadIdx.x;
  int row16 = lane & 15, kgrp = lane >> 4;
  int qb0 = qt * 32;

  const u16* Qp = Qb + ((size_t)(b * NHEAD + h) * S_LEN + qb0) * DHEAD;
  const u16* Kp = Kb + (size_t)(b * NHEAD + h) * S_LEN * DHEAD;
  const u16* Vt = xT + (size_t)b * DHEAD * S_LEN;

  bf16x8 aq[2][4];
#pragma unroll
  for (int r = 0; r < 2; ++r)
#pragma unroll
    for (int kc = 0; kc < 4; ++kc)
      aq[r][kc] = *(const bf16x8*)(Qp + (r * 16 + row16) * DHEAD + kc * 32 + kgrp * 8);

  f32x4 y[2][8];
#pragma unroll
  for (int r = 0; r < 2; ++r)
#pragma unroll
    for (int nc = 0; nc < 8; ++nc) y[r][nc] = zero4();
  f32x4 rs[2];
  rs[0] = zero4();
  rs[1] = zero4();

  __shared__ __align__(16) u16 plds[2][32][40];

  bf16x8 kA[8], kB[8], vA[8], vB[8];

  auto loadK = [&](bf16x8 (&dst)[8], int k0) {
#pragma unroll
    for (int nk = 0; nk < 2; ++nk)
#pragma unroll
      for (int kc = 0; kc < 4; ++kc)
        dst[nk * 4 + kc] = *(const bf16x8*)(Kp + (size_t)(k0 + nk * 16 + row16) * DHEAD +
                                            kc * 32 + kgrp * 8);
  };
  auto loadV = [&](bf16x8 (&dst)[8], int k0) {
#pragma unroll
    for (int nc = 0; nc < 8; ++nc)
      dst[nc] = *(const bf16x8*)(Vt + (size_t)(nc * 16 + row16) * S_LEN + k0 + kgrp * 8);
  };

  const float c2 = 0.12754274816295166f;    // (1/sqrt(128)) * log2(e)
  const float clip2 = 14.426950408889634f;  // 10 * log2(e)

  auto qk = [&](bf16x8 (&kk)[8], f32x4 (&sc)[2][2]) {
    sc[0][0] = zero4(); sc[0][1] = zero4(); sc[1][0] = zero4(); sc[1][1] = zero4();
#pragma unroll
    for (int nk = 0; nk < 2; ++nk)
#pragma unroll
      for (int kcc = 0; kcc < 4; ++kcc) {
        sc[0][nk] = mfma16(aq[0][kcc], kk[nk * 4 + kcc], sc[0][nk]);
        sc[1][nk] = mfma16(aq[1][kcc], kk[nk * 4 + kcc], sc[1][nk]);
      }
  };

  // branchless diag mask: key>qrow only possible on the diagonal tile.
  auto smax = [&](f32x4 (&sc)[2][2], int k0, u16 (*pl)[40]) {
#pragma unroll
    for (int r = 0; r < 2; ++r)
#pragma unroll
      for (int nk = 0; nk < 2; ++nk) {
        int key = k0 + nk * 16 + row16;
#pragma unroll
        for (int i = 0; i < 4; ++i) {
          float v = sc[r][nk][i] * c2;
          v = fminf(fmaxf(v, -clip2), clip2);
          float pcur = __builtin_amdgcn_exp2f(v);
          int qrow = qb0 + r * 16 + kgrp * 4 + i;
          pcur = (key > qrow) ? 0.0f : pcur;
          rs[r][i] += pcur;
          pl[r * 16 + kgrp * 4 + i][nk * 16 + row16] = f2b(pcur);
        }
      }
  };

  auto pv = [&](u16 (*pl)[40], bf16x8 (&vv)[8]) {
    bf16x8 ap0 = *(const bf16x8*)&pl[row16][kgrp * 8];
    bf16x8 ap1 = *(const bf16x8*)&pl[16 + row16][kgrp * 8];
#pragma unroll
    for (int nc = 0; nc < 8; ++nc) {
      y[0][nc] = mfma16(ap0, vv[nc], y[0][nc]);
      y[1][nc] = mfma16(ap1, vv[nc], y[1][nc]);
    }
  };

  int n = qt + 1;
  int t = 0;
  loadK(kA, 0);
  if (n & 1) {
    loadV(vA, 0);
    f32x4 scA[2][2];
    qk(kA, scA);
    smax(scA, 0, plds[0]);
    pv(plds[0], vA);
    t = 1;
    if (t < n) loadK(kA, 32);
  }
  while (t < n) {
    int k0 = t * 32;
    loadV(vA, k0);
    loadK(kB, k0 + 32);
    f32x4 scA[2][2];
    qk(kA, scA);
    smax(scA, k0, plds[0]);           // VALU; overlaps QK_A drain
    if (t + 2 < n) loadK(kA, k0 + 64);
    loadV(vB, k0 + 32);
    f32x4 scB[2][2];
    qk(kB, scB);                      // MFMA; interleaves with smax_A
    pv(plds[0], vA);                  // LDS+MFMA
    smax(scB, k0 + 32, plds[1]);      // VALU; interleaves with PV_A
    pv(plds[1], vB);
    t += 2;
  }

  // reduce rs over the 16 row16 lanes of each kgrp group
#pragma unroll
  for (int r = 0; r < 2; ++r)
#pragma unroll
    for (int i = 0; i < 4; ++i) {
      float v = rs[r][i];
      v += __shfl_xor(v, 1, 64);
      v += __shfl_xor(v, 2, 64);
      v += __shfl_xor(v, 4, 64);
      v += __shfl_xor(v, 8, 64);
      rs[r][i] = v;
    }

  u16* Yp = Yb + ((size_t)b * S_LEN + qb0) * (NHEAD * DHEAD) + h * DHEAD;
#pragma unroll
  for (int r = 0; r < 2; ++r) {
    float inv[4];
#pragma unroll
    for (int i = 0; i < 4; ++i) inv[i] = 1.0f / rs[r][i];
#pragma unroll
    for (int nc = 0; nc < 8; ++nc)
#pragma unroll
      for (int i = 0; i < 4; ++i)
        Yp[(size_t)(r * 16 + kgrp * 4 + i) * (NHEAD * DHEAD) + nc * 16 + row16] =
            f2b(y[r][nc][i] * inv[i]);
  }
}

// ---------------- output projection: 4 waves/block ----------------
__global__ __launch_bounds__(256) void k_oproj(const u16* __restrict__ Yb,
                                               const u16* __restrict__ WoB,
                                               float* __restrict__ out) {
  int wid = threadIdx.x >> 6;
  int lane = threadIdx.x & 63;
  int mb = (blockIdx.x * 4 + wid) * 32 + blockIdx.y * 16;
  int nb = blockIdx.z * 64;
  int row16 = lane & 15, kgrp = lane >> 4;
  f32x4 acc[4];
#pragma unroll
  for (int nc = 0; nc < 4; ++nc) acc[nc] = zero4();
#pragma unroll 4
  for (int kc = 0; kc < 32; ++kc) {
    bf16x8 a0 = *(const bf16x8*)(Yb + (size_t)(mb + row16) * 1024 + kc * 32 + kgrp * 8);
#pragma unroll
    for (int nc = 0; nc < 4; ++nc) {
      bf16x8 bw =
          *(const bf16x8*)(WoB + (size_t)(nb + nc * 16 + row16) * 1024 + kc * 32 + kgrp * 8);
      acc[nc] = mfma16(a0, bw, acc[nc]);
    }
  }
#pragma unroll
  for (int nc = 0; nc < 4; ++nc)
#pragma unroll
    for (int i = 0; i < 4; ++i)
      out[(size_t)(mb + kgrp * 4 + i) * DHEAD + nb + nc * 16 + row16] = acc[nc][i];
}

extern "C" void kernel_launch(void* const* d_in, const int* in_sizes, int n_in,
                              void* d_out, int out_size, void* d_ws, size_t ws_size,
                              hipStream_t stream) {
  const float* x = (const float*)d_in[0];
  const float* Wq = (const float*)d_in[1];
  const float* Wk = (const float*)d_in[2];
  const float* Wo = (const float*)d_in[3];
  float* out = (float*)d_out;

  char* ws = (char*)d_ws;
  size_t off = 0;
  auto alloc = [&](size_t bytes) -> void* {
    void* p = ws + off;
    off += (bytes + 255) & ~(size_t)255;
    return p;
  };
  const size_t nx = (size_t)NBATCH * S_LEN * DHEAD;
  const size_t nqk = (size_t)NBATCH * NHEAD * S_LEN * DHEAD;
  u16* xb = (u16*)alloc(nx * 2);
  u16* xT = (u16*)alloc(nx * 2);
  u16* Wqt = (u16*)alloc((size_t)NHEAD * DHEAD * DHEAD * 2);
  u16* Wkt = (u16*)alloc((size_t)NHEAD * DHEAD * DHEAD * 2);
  u16* WoB = (u16*)alloc((size_t)DHEAD * NHEAD * DHEAD * 2);
  u16* Qb = (u16*)alloc(nqk * 2);
  u16* Kb = (u16*)alloc(nqk * 2);
  u16* Yb = (u16*)alloc(nqk * 2);
  (void)ws_size;

  k_conv_x<<<dim3(nx / 256), dim3(256), 0, stream>>>(x, xb, xT);
  k_conv_w<<<dim3(131072 / 256), dim3(256), 0, stream>>>(Wq, Wk, Wo, Wqt, Wkt, WoB);
  k_proj<<<dim3(S_LEN / 32 / 4, NHEAD, 2 * NBATCH), dim3(256), 0, stream>>>(xb, Wqt, Wkt, Qb, Kb);
  k_attn<<<dim3((S_LEN / 32) * NHEAD * NBATCH), dim3(64), 0, stream>>>(Qb, Kb, xT, Yb);
  k_oproj<<<dim3((NBATCH * S_LEN) / 32 / 4, 2, 2), dim3(256), 0, stream>>>(Yb, WoB, out);
}